// Round 1
// baseline (433.350 us; speedup 1.0000x reference)
//
#include <hip/hip_runtime.h>
#include <math.h>

#define L_SIG 65537
#define NH    65536     // half-size complex FFT length (NFFT/2)
#define NSIG  256
#define PI_F  3.14159265358979323846f

struct c32 { float x, y; };
__device__ __forceinline__ c32 mkc(float a, float b){ c32 r; r.x=a; r.y=b; return r; }
__device__ __forceinline__ c32 cadd(c32 a, c32 b){ return mkc(a.x+b.x, a.y+b.y); }
__device__ __forceinline__ c32 csub(c32 a, c32 b){ return mkc(a.x-b.x, a.y-b.y); }
__device__ __forceinline__ c32 cmul(c32 a, c32 b){ return mkc(a.x*b.x - a.y*b.y, a.x*b.y + a.y*b.x); }

// ---------------- 16-point FFT in registers (radix-4 x 2) ------------------
// U[c] = sum_b t[b] * e^{S*2*pi*i*b*c/16}
template<int S>
__device__ __forceinline__ void fft16(c32 v[16]) {
  constexpr float C16[16] = {
    1.0f, 0.9238795325112867f, 0.7071067811865476f, 0.3826834323650898f,
    0.0f,-0.3826834323650898f,-0.7071067811865476f,-0.9238795325112867f,
   -1.0f,-0.9238795325112867f,-0.7071067811865476f,-0.3826834323650898f,
    0.0f, 0.3826834323650898f, 0.7071067811865476f, 0.9238795325112867f };
  constexpr float S16[16] = {
    0.0f, 0.3826834323650898f, 0.7071067811865476f, 0.9238795325112867f,
    1.0f, 0.9238795325112867f, 0.7071067811865476f, 0.3826834323650898f,
    0.0f,-0.3826834323650898f,-0.7071067811865476f,-0.9238795325112867f,
   -1.0f,-0.9238795325112867f,-0.7071067811865476f,-0.3826834323650898f };
  c32 s[16];
  #pragma unroll
  for (int b0 = 0; b0 < 4; ++b0) {
    c32 x0=v[b0], x1=v[b0+4], x2=v[b0+8], x3=v[b0+12];
    c32 u0=cadd(x0,x2), u1=csub(x0,x2), u2=cadd(x1,x3), u3=csub(x1,x3);
    c32 iu3 = mkc(-u3.y, u3.x);
    c32 yy[4];
    yy[0]=cadd(u0,u2); yy[2]=csub(u0,u2);
    if (S < 0) { yy[1]=csub(u1,iu3); yy[3]=cadd(u1,iu3); }
    else       { yy[1]=cadd(u1,iu3); yy[3]=csub(u1,iu3); }
    #pragma unroll
    for (int c0 = 0; c0 < 4; ++c0) {
      const int p = (b0*c0) & 15;
      c32 w = mkc(C16[p], (S<0) ? -S16[p] : S16[p]);
      s[c0*4 + b0] = cmul(yy[c0], w);
    }
  }
  #pragma unroll
  for (int c0 = 0; c0 < 4; ++c0) {
    c32 x0=s[c0*4+0], x1=s[c0*4+1], x2=s[c0*4+2], x3=s[c0*4+3];
    c32 u0=cadd(x0,x2), u1=csub(x0,x2), u2=cadd(x1,x3), u3=csub(x1,x3);
    c32 iu3 = mkc(-u3.y, u3.x);
    c32 yy[4];
    yy[0]=cadd(u0,u2); yy[2]=csub(u0,u2);
    if (S < 0) { yy[1]=csub(u1,iu3); yy[3]=cadd(u1,iu3); }
    else       { yy[1]=cadd(u1,iu3); yy[3]=csub(u1,iu3); }
    v[c0+0]=yy[0]; v[c0+4]=yy[1]; v[c0+8]=yy[2]; v[c0+12]=yy[3];
  }
}

// ---------------- 256-point FFT, 16-thread team --------------------------
// In : thread r holds x[r + 16*j] in v[j]
// Out: thread r holds X[r + 16*j] in v[j];  X[k]=sum x[n] e^{S*2pi*i*nk/256}
// 16 teams per 256-thread block; team id = t (0..15), role = r (0..15).
// smem must hold >= 4096 c32, shared by whole block.
template<int S>
__device__ __forceinline__ void fft256_team(c32 v[16], int r, int t, c32* sm) {
  fft16<S>(v);
  // twiddle W256^{S*r*c}, incremental rotation
  float ang = (float)S * (2.0f*PI_F/256.0f) * (float)r;
  c32 st; __sincosf(ang, &st.y, &st.x);
  c32 w = st;
  #pragma unroll
  for (int c = 1; c < 16; ++c) { v[c] = cmul(v[c], w); w = cmul(w, st); }
  __syncthreads();
  #pragma unroll
  for (int c = 0; c < 16; ++c) sm[c*256 + r*16 + t] = v[c];
  __syncthreads();
  #pragma unroll
  for (int a = 0; a < 16; ++a) v[a] = sm[r*256 + a*16 + t];
  fft16<S>(v);
}

// ---------------- prep: mod_depth, pm, spectral line table ----------------
__global__ __launch_bounds__(256) void k_prep(const float* __restrict__ b1,
    const float* __restrict__ W2, const float* __restrict__ b2,
    const float* __restrict__ W3, const float* __restrict__ b3,
    const float* __restrict__ hp, const float* __restrict__ fw,
    float* __restrict__ pm_out, int* __restrict__ hidx, float* __restrict__ amp) {
  __shared__ float red[256];
  __shared__ float s_md, s_pm;
  int t = threadIdx.x;
  if (t == 0) {
    float h1[32], h2[16];
    for (int i=0;i<32;i++){ float z = b1[i]; h1[i] = z > 0.f ? z : 0.f; }
    for (int o=0;o<16;o++){ float acc = b2[o];
      for (int i=0;i<32;i++) acc += h1[i]*W2[i*16+o];
      h2[o] = acc > 0.f ? acc : 0.f; }
    float md = b3[1];
    for (int i=0;i<16;i++) md += h2[i]*W3[i*8+1];
    s_md = md;
  }
  __syncthreads();
  float md = s_md;
  float partial = 0.f;
  for (int tt = t; tt < 65537; tt += 256) {
    int ci = (tt * 8) / 65537;     // == floor(t*8/65537) in f32, verified safe
    float cs = hp[ci*4+0] + hp[ci*4+1] + hp[ci*4+2] + hp[ci*4+3];
    float ang = (6.2831853071795864769f * (float)tt) / 65537.0f;
    partial += cs * (1.f + md * sinf(ang));
  }
  red[t] = partial;
  __syncthreads();
  for (int s = 128; s > 0; s >>= 1) { if (t < s) red[t] += red[t+s]; __syncthreads(); }
  if (t == 0) { s_pm = red[0] / (65537.0f * 4.0f); pm_out[0] = s_pm; }
  __syncthreads();
  if (t < 40) {
    const double SPECF[8] = {7.83, 528.0, 396.0, 2.5, 14.1, 432.0, 6.0, 30.0};
    int j = t / 5, mi = t % 5;
    double mult = (double)(mi + 1);
    double hf = SPECF[j] * mult;                 // all < 11025, none skipped
    double ratio = hf * (131072.0 / 22050.0);    // bin index (none near x.5)
    hidx[t] = (int)floor(ratio + 0.5);
    amp[t] = (float)((double)fw[j] * pow(mult, -1.2) * (1.0 + (double)s_pm));
  }
}

// ---------------- gain curve: bands + 40 spectral line windows ------------
__global__ __launch_bounds__(256) void k_gain(float* __restrict__ gain,
    const float* __restrict__ bw, const int* __restrict__ hidx,
    const float* __restrict__ amp) {
  int i = blockIdx.x*256 + threadIdx.x;
  if (i >= 65537) return;
  float f = (float)((double)i * (22050.0/131072.0));
  float g = 1.0f;
  constexpr double LO[6] = {1,4,8,13,30,100};
  constexpr double HI[6] = {4,8,13,30,100,200};
  #pragma unroll
  for (int k = 0; k < 6; ++k) {
    float center = (float)(0.5*(LO[k]+HI[k]));
    float sig    = (float)(0.25*(HI[k]-LO[k]));   // (width)/2 with width=(hi-lo)/2
    float dm = (f - center)/sig;
    float mask = expf(-0.5f*dm*dm);
    if (f < (float)LO[k] || f > (float)HI[k]) mask = 0.f;
    float ang = (float)(6.283185307179586*0.5*(LO[k]+HI[k])) * (float)i / 22050.0f;
    g *= 1.0f + mask * bw[k] * (1.0f + 0.2f*sinf(ang));
  }
  for (int l = 0; l < 40; ++l) {
    int d = i - hidx[l];
    if (d >= -15 && d <= 15) {
      float dd = (float)d * 0.2f;                 // /(ws/3)=5
      g *= 1.0f + amp[l] * expf(-0.5f*dd*dd);
    }
  }
  gain[i] = g;
}

// ---------------- forward pass 1: pack + column FFT + 4-step twiddle ------
// x (real, per-signal 65537 floats) -> A[k2*256 + n1] per signal
__global__ __launch_bounds__(256) void k_fwd1(const float* __restrict__ x,
                                              c32* __restrict__ A, int s0) {
  __shared__ c32 sm[4112];
  int b = blockIdx.x; int sl = b >> 4; int g = b & 15;
  int t = threadIdx.x & 15, r = threadIdx.x >> 4;
  int n1 = g*16 + t;
  const float* xb = x + (size_t)(s0 + sl) * L_SIG;
  c32 v[16];
  #pragma unroll
  for (int j = 0; j < 16; ++j) {
    int n = n1 + 256*r + 4096*j;         // packed index; z[n]=x[2n]+i x[2n+1]
    c32 z = mkc(0.f, 0.f);
    if (n < 32768)       { z.x = xb[2*n]; z.y = xb[2*n+1]; }
    else if (n == 32768) { z.x = xb[65536]; }
    v[j] = z;
  }
  fft256_team<-1>(v, r, t, sm);
  // four-step twiddle W65536^{-n1*k2}, k2 = r+16j
  float a0 = -(2.0f*PI_F/65536.0f) * (float)(n1 * r);
  float a1 = -(2.0f*PI_F/4096.0f)  * (float)n1;
  c32 wb, wst;
  __sincosf(a0, &wb.y, &wb.x);
  __sincosf(a1, &wst.y, &wst.x);
  #pragma unroll
  for (int j = 0; j < 16; ++j) { v[j] = cmul(v[j], wb); wb = cmul(wb, wst); }
  // stage + coalesced store: A[sl][k2*256 + n1]
  __syncthreads();
  #pragma unroll
  for (int j = 0; j < 16; ++j) sm[(r + 16*j)*16 + t] = v[j];
  __syncthreads();
  c32* Ab = A + (size_t)sl * NH;
  int u = threadIdx.x & 15, k2b = threadIdx.x >> 4;
  #pragma unroll
  for (int m = 0; m < 16; ++m) {
    int k2 = k2b + 16*m;
    Ab[(size_t)k2*256 + g*16 + u] = sm[k2*16 + u];
  }
}

// ---------------- forward pass 2: row FFT -> Z natural order --------------
__global__ __launch_bounds__(256) void k_fwd2(const c32* __restrict__ A,
                                              c32* __restrict__ B) {
  __shared__ c32 sm[4112];
  int b = blockIdx.x; int sl = b >> 4; int g = b & 15;
  int t = threadIdx.x & 15, r = threadIdx.x >> 4;
  const c32* Ab = A + (size_t)sl * NH;
  #pragma unroll
  for (int m = 0; m < 16; ++m) {
    int flat = threadIdx.x + 256*m;
    int rl = flat >> 8, n1 = flat & 255;
    sm[rl*257 + n1] = Ab[(size_t)(g*16 + rl)*256 + n1];
  }
  __syncthreads();
  c32 v[16];
  #pragma unroll
  for (int j = 0; j < 16; ++j) v[j] = sm[t*257 + r + 16*j];
  fft256_team<-1>(v, r, t, sm);
  c32* Bb = B + (size_t)sl * NH;
  int k2 = g*16 + t;
  #pragma unroll
  for (int j = 0; j < 16; ++j) Bb[(size_t)k2 + 256*(r + 16*j)] = v[j];
}

// ---------------- mid: unpack + gain + mag smooth + repack + 1/N ----------
__device__ __forceinline__ c32 unpack_gain(c32 zk, c32 zb, int k,
                                           const float* __restrict__ gain,
                                           float* mag) {
  // X[k] = 0.5(zk + conj(zb)) - 0.5 i W^k (zk - conj(zb)),  W = e^{-i pi/65536}
  c32 Aa = mkc(0.5f*(zk.x + zb.x), 0.5f*(zk.y - zb.y));
  c32 Bm = mkc(0.5f*(zk.x - zb.x), 0.5f*(zk.y + zb.y));
  float sw, cw; __sincosf(-(PI_F/65536.0f) * (float)k, &sw, &cw);
  c32 miw = mkc(sw, -cw);                 // -i * W^k
  c32 X = cadd(Aa, cmul(miw, Bm));
  float g = gain[k];
  X.x *= g; X.y *= g;
  *mag = sqrtf(X.x*X.x + X.y*X.y);
  return X;
}

__global__ __launch_bounds__(256) void k_mid(const c32* __restrict__ Z,
    c32* __restrict__ Zc, const float* __restrict__ gain) {
  __shared__ c32 ZL[258], ZH[258], XL[258], XH[258];
  __shared__ float ML[258], MH[258];
  int b = blockIdx.x; int s = b >> 7; int blk = b & 127;
  int k0 = blk << 8;
  const c32* Zs = Z + (size_t)s * NH;
  c32* Os = Zc + (size_t)s * NH;
  int t = threadIdx.x;
  for (int e = t; e < 258; e += 256) {
    int kl = k0 - 1 + e;
    c32 zl = mkc(0.f,0.f);
    if (kl >= 0) zl = Zs[kl & (NH-1)];
    ZL[e] = zl;
    int kh = NH - k0 - 256 + e;
    ZH[e] = Zs[kh & (NH-1)];
  }
  __syncthreads();
  for (int e = t; e < 258; e += 256) {
    {
      int k = k0 - 1 + e;
      if (k >= 0) { float m; XL[e] = unpack_gain(ZL[e], ZH[257-e], k, gain, &m); ML[e] = m; }
      else        { XL[e] = mkc(0.f,0.f); ML[e] = 0.f; }
    }
    {
      int K = NH - k0 - 256 + e;
      if (K <= 65536) { float m; XH[e] = unpack_gain(ZH[e], ZL[257-e], K, gain, &m); MH[e] = m; }
      else            { XH[e] = mkc(0.f,0.f); MH[e] = 0.f; }
    }
  }
  __syncthreads();
  {
    int q = t; int k = k0 + q;
    float m = ML[q+1];
    float msm = (k == 0) ? m : 0.7f*m + 0.15f*(ML[q] + ML[q+2]);
    c32 Xl = XL[q+1];
    c32 XcL = (m > 0.f) ? mkc(Xl.x*(msm/m), Xl.y*(msm/m)) : mkc(msm, 0.f);
    int K = NH - k;
    int eH = 256 - q;
    float mh = MH[eH];
    float msh = (K == 65536) ? mh : 0.7f*mh + 0.15f*(MH[eH-1] + MH[eH+1]);
    c32 Xh = XH[eH];
    c32 XcH = (mh > 0.f) ? mkc(Xh.x*(msh/mh), Xh.y*(msh/mh)) : mkc(msh, 0.f);
    // E' = 0.5(XcL + conj(XcH)); O' = 0.5 W^{-k} (XcL - conj(XcH))
    c32 E = mkc(0.5f*(XcL.x + XcH.x), 0.5f*(XcL.y - XcH.y));
    c32 D = mkc(0.5f*(XcL.x - XcH.x), 0.5f*(XcL.y + XcH.y));
    float so, co; __sincosf((PI_F/65536.0f) * (float)k, &so, &co);
    c32 O = cmul(mkc(co, so), D);
    const float invN = 1.0f/65536.0f;
    Os[k] = mkc((E.x - O.y)*invN, (E.y + O.x)*invN);              // E' + iO'
    if (k != 0) Os[K] = mkc((E.x + O.y)*invN, (O.x - E.y)*invN);  // conj(E')+i conj(O')
  }
  if (blk == 127 && t == 0) {   // self-paired bin k = 32768
    float m = ML[257];
    float msm = 0.7f*m + 0.15f*(ML[256] + MH[1]);
    c32 Xl = XL[257];
    c32 Xc = (m > 0.f) ? mkc(Xl.x*(msm/m), Xl.y*(msm/m)) : mkc(msm, 0.f);
    // E' = Re(Xc);  O' = W^{-32768} * i*Im(Xc) = i * (i Im) = -Im(Xc)
    const float invN = 1.0f/65536.0f;
    Os[32768] = mkc(Xc.x*invN, -Xc.y*invN);
  }
}

// ---------------- inverse pass 1: column FFT (+) + twiddle ----------------
__global__ __launch_bounds__(256) void k_inv1(const c32* __restrict__ Zc,
                                              c32* __restrict__ B) {
  __shared__ c32 sm[4112];
  int b = blockIdx.x; int sl = b >> 4; int g = b & 15;
  int t = threadIdx.x & 15, r = threadIdx.x >> 4;
  int a = g*16 + t;
  const c32* Zs = Zc + (size_t)sl * NH;
  c32 v[16];
  #pragma unroll
  for (int j = 0; j < 16; ++j) v[j] = Zs[(size_t)a + 256*(r + 16*j)];
  fft256_team<1>(v, r, t, sm);
  float a0 = (2.0f*PI_F/65536.0f) * (float)(a * r);
  float a1 = (2.0f*PI_F/4096.0f)  * (float)a;
  c32 wb, wst;
  __sincosf(a0, &wb.y, &wb.x);
  __sincosf(a1, &wst.y, &wst.x);
  #pragma unroll
  for (int j = 0; j < 16; ++j) { v[j] = cmul(v[j], wb); wb = cmul(wb, wst); }
  __syncthreads();
  #pragma unroll
  for (int j = 0; j < 16; ++j) sm[(r + 16*j)*16 + t] = v[j];
  __syncthreads();
  c32* Bb = B + (size_t)sl * NH;
  int u = threadIdx.x & 15, m2b = threadIdx.x >> 4;
  #pragma unroll
  for (int m = 0; m < 16; ++m) {
    int m2 = m2b + 16*m;
    Bb[(size_t)m2*256 + g*16 + u] = sm[m2*16 + u];
  }
}

// ---------------- inverse pass 2: row FFT (+) -> real output --------------
__global__ __launch_bounds__(256) void k_inv2(const c32* __restrict__ B,
                                              float* __restrict__ out, int s0) {
  __shared__ c32 sm[4112];
  int b = blockIdx.x; int sl = b >> 4; int g = b & 15;
  int t = threadIdx.x & 15, r = threadIdx.x >> 4;
  const c32* Bb = B + (size_t)sl * NH;
  #pragma unroll
  for (int m = 0; m < 16; ++m) {
    int flat = threadIdx.x + 256*m;
    int rl = flat >> 8, aa = flat & 255;
    sm[rl*257 + aa] = Bb[(size_t)(g*16 + rl)*256 + aa];
  }
  __syncthreads();
  c32 v[16];
  #pragma unroll
  for (int j = 0; j < 16; ++j) v[j] = sm[t*257 + r + 16*j];
  fft256_team<1>(v, r, t, sm);
  float* yb = out + (size_t)(s0 + sl) * L_SIG;
  int m2 = g*16 + t;
  #pragma unroll
  for (int j = 0; j < 16; ++j) {
    int m1 = r + 16*j;
    if (m1 <= 127) {
      int m = m2 + 256*m1;          // m <= 32767 -> y[2m], y[2m+1] valid
      yb[2*m]   = v[j].x;
      yb[2*m+1] = v[j].y;
    } else if (m1 == 128 && m2 == 0) {
      yb[65536] = v[j].x;           // last sample y[L-1]
    }
  }
}

// --------------------------------------------------------------------------
extern "C" void kernel_launch(void* const* d_in, const int* in_sizes, int n_in,
                              void* d_out, int out_size, void* d_ws, size_t ws_size,
                              hipStream_t stream) {
  const float* x  = (const float*)d_in[0];
  const float* bw = (const float*)d_in[1];
  const float* fw = (const float*)d_in[2];
  const float* hp = (const float*)d_in[3];
  // d_in[4] = W1: mathematically unused (tn==0 at the only sampled row)
  const float* b1 = (const float*)d_in[5];
  const float* W2 = (const float*)d_in[6];
  const float* b2 = (const float*)d_in[7];
  const float* W3 = (const float*)d_in[8];
  const float* b3 = (const float*)d_in[9];
  float* out = (float*)d_out;
  char* ws = (char*)d_ws;

  const size_t perSig = (size_t)NH * sizeof(c32);              // 512 KiB / signal / buffer
  const size_t tail   = (size_t)L_SIG * sizeof(float) + 512;   // gain + scalars
  size_t cap = (ws_size > tail) ? (ws_size - tail) / (2*perSig) : 1;
  int chunk = (cap >= (size_t)NSIG) ? NSIG : (cap < 1 ? 1 : (int)cap);

  c32*   A    = (c32*)ws;
  c32*   Bb   = (c32*)(ws + (size_t)chunk*perSig);
  float* gain = (float*)(ws + 2*(size_t)chunk*perSig);
  float* pm   = gain + L_SIG;
  int*   hidx = (int*)(pm + 1);
  float* amp  = (float*)(hidx + 40);

  k_prep<<<1, 256, 0, stream>>>(b1, W2, b2, W3, b3, hp, fw, pm, hidx, amp);
  k_gain<<<257, 256, 0, stream>>>(gain, bw, hidx, amp);

  for (int s0 = 0; s0 < NSIG; s0 += chunk) {
    int S = (NSIG - s0 < chunk) ? (NSIG - s0) : chunk;
    k_fwd1<<<S*16, 256, 0, stream>>>(x, A, s0);
    k_fwd2<<<S*16, 256, 0, stream>>>(A, Bb);
    k_mid <<<S*128,256, 0, stream>>>(Bb, A, gain);
    k_inv1<<<S*16, 256, 0, stream>>>(A, Bb);
    k_inv2<<<S*16, 256, 0, stream>>>(Bb, out, s0);
  }
}